// Round 1
// baseline (428.579 us; speedup 1.0000x reference)
//
#include <hip/hip_runtime.h>
#include <stdint.h>

// Problem constants
#define kB  16384
#define kD  1024
#define kDE 512

typedef __bf16 bf16x8 __attribute__((ext_vector_type(8)));
typedef float  f32x4  __attribute__((ext_vector_type(4)));

__device__ __forceinline__ unsigned short f2bf(float f) {
    union { float f; unsigned u; } v; v.f = f;
    unsigned r = v.u + 0x7FFFu + ((v.u >> 16) & 1u);   // round-to-nearest-even
    return (unsigned short)(r >> 16);
}

__device__ __forceinline__ void async16(unsigned short* lds, const unsigned short* g) {
    __builtin_amdgcn_global_load_lds(
        (const __attribute__((address_space(1))) unsigned int*)g,
        (__attribute__((address_space(3))) unsigned int*)lds, 16, 0, 0);
}

// ---------------- prep: transpose + convert weights to bf16 ----------------
// Wt[slot][n=512][k=1024], slot: 0-3 shared, 4-7 t0-specific, 8-11 t1-specific
__global__ __launch_bounds__(256) void prep_w(const float* __restrict__ Wsh,
                                              const float* __restrict__ Wsp,
                                              unsigned short* __restrict__ Wt) {
    __shared__ float tile[32][33];
    const int slot = blockIdx.z;
    const int k0 = blockIdx.x * 32;
    const int n0 = blockIdx.y * 32;
    const float* src = (slot < 4) ? (Wsh + (size_t)slot * kD * kDE)
                                  : (Wsp + (size_t)(slot - 4) * kD * kDE);
    const int tx = threadIdx.x, ty = threadIdx.y;
#pragma unroll
    for (int i = 0; i < 4; i++)
        tile[ty + i * 8][tx] = src[(size_t)(k0 + ty + i * 8) * kDE + n0 + tx];
    __syncthreads();
    unsigned short* dst = Wt + (size_t)slot * kDE * kD;
#pragma unroll
    for (int i = 0; i < 4; i++)
        dst[(size_t)(n0 + ty + i * 8) * kD + k0 + tx] = f2bf(tile[tx][ty + i * 8]);
}

// bias concat: bc[t][e][n]  (2*8*512)
__global__ __launch_bounds__(256) void prep_b(const float* __restrict__ bsh,
                                              const float* __restrict__ bsp,
                                              float* __restrict__ bc) {
    int i = blockIdx.x * 256 + threadIdx.x;       // 0..8191
    int n = i & 511, e = (i >> 9) & 7, t = i >> 12;
    bc[i] = (e < 4) ? bsh[e * 512 + n] : bsp[(t * 4 + (e - 4)) * 512 + n];
}

// ------------- fused x fp32->bf16 conversion + gate softmax ---------------
// one wave per (t,b) row; xb[t][b][d] bf16; g[t][b][8] fp32
__global__ __launch_bounds__(256) void conv_gate(
    const float* __restrict__ x0, const float* __restrict__ x1,
    const float* __restrict__ Wg, const float* __restrict__ bg,
    unsigned short* __restrict__ xb, float* __restrict__ g) {
    const int wid = threadIdx.x >> 6, lane = threadIdx.x & 63;
    const int r = blockIdx.x * 4 + wid;           // 0..32767
    const int t = r >> 14, b = r & 16383;
    const float* xrow = (t ? x1 : x0) + (size_t)b * kD;
    unsigned short* xbrow = xb + (size_t)(t * kB + b) * kD;
    const float* Wgt = Wg + t * kD * 8;
    float p[8] = {0.f,0.f,0.f,0.f,0.f,0.f,0.f,0.f};
#pragma unroll
    for (int it = 0; it < 4; it++) {
        const int d0 = it * 256 + lane * 4;
        const float4 v = *(const float4*)(xrow + d0);
        ushort4 h;
        h.x = f2bf(v.x); h.y = f2bf(v.y); h.z = f2bf(v.z); h.w = f2bf(v.w);
        *(ushort4*)(xbrow + d0) = h;
        const float xv[4] = {v.x, v.y, v.z, v.w};
#pragma unroll
        for (int j = 0; j < 4; j++) {
            const float* wrow = Wgt + (size_t)(d0 + j) * 8;
#pragma unroll
            for (int e = 0; e < 8; e++) p[e] += xv[j] * wrow[e];
        }
    }
#pragma unroll
    for (int e = 0; e < 8; e++) {
        float v = p[e];
#pragma unroll
        for (int s = 1; s < 64; s <<= 1) v += __shfl_xor(v, s, 64);
        p[e] = v;
    }
    float lg[8];
#pragma unroll
    for (int e = 0; e < 8; e++) lg[e] = p[e] + bg[t * 8 + e];
    float mx = lg[0];
#pragma unroll
    for (int e = 1; e < 8; e++) mx = fmaxf(mx, lg[e]);
    float s = 0.f;
#pragma unroll
    for (int e = 0; e < 8; e++) { lg[e] = __expf(lg[e] - mx); s += lg[e]; }
    const float inv = 1.f / s;
    if (lane == 0) {
        float* gp = g + (size_t)(t * kB + b) * 8;
        float4 g0 = {lg[0]*inv, lg[1]*inv, lg[2]*inv, lg[3]*inv};
        float4 g1 = {lg[4]*inv, lg[5]*inv, lg[6]*inv, lg[7]*inv};
        *(float4*)gp = g0;
        *(float4*)(gp + 4) = g1;
    }
}

// --------------------------- fused MoE GEMM -------------------------------
// grid (row-tile 0..127, col-tile 0..3, t 0..1), 256 threads (4 waves, 2x2),
// tile 128x128, BK=64, single-buffer 2-barrier K-loop, gload_lds width 16,
// XOR-swizzled LDS (pre-swizzled global source + swizzled ds_read).
__global__ __launch_bounds__(256, 2) void moe_gemm(
    const unsigned short* __restrict__ xb, const unsigned short* __restrict__ Wt,
    const float* __restrict__ g, const float* __restrict__ bc,
    float* __restrict__ out) {
    __shared__ __align__(16) unsigned short As[128 * 64];   // [row][k] swizzled
    __shared__ __align__(16) unsigned short Bs[128 * 64];   // [n][k]   swizzled
    const int rt = blockIdx.x, ct = blockIdx.y, t = blockIdx.z;
    const int tid = threadIdx.x, wid = tid >> 6, lane = tid & 63;
    const int wr = wid >> 1, wc = wid & 1;
    const int rowBase = rt * 128, n0 = ct * 128;

    // staging: lane covers LDS linear bytes (wid*4+i)*1024 + lane*16
    // -> row = wid*32 + i*8 + (lane>>3), k chunk swizzled by row&7
    const int srow = wid * 32 + (lane >> 3);
    const int swzk = (((lane & 7) ^ ((lane >> 3) & 7)) << 3);   // element offset
    const unsigned short* aG0 = xb + (size_t)t * kB * kD +
                                (size_t)(rowBase + srow) * kD + swzk;
    unsigned short* aL = As + wid * 2048;
    unsigned short* bL = Bs + wid * 2048;

    // fragment reads: row = (l&15), k-group g=(l>>4); chunk = (ks*4+g)^(row&7)
    const int rA = wr * 64 + (lane & 15);
    const int rB = wc * 64 + (lane & 15);
    const int c0 = (((lane >> 4) ^ (lane & 7)) << 3);  // ks=0 short-offset; ks=1: ^32

    f32x4 oacc[4][4];
#pragma unroll
    for (int m = 0; m < 4; m++)
#pragma unroll
        for (int n = 0; n < 4; n++) oacc[m][n] = (f32x4){0.f, 0.f, 0.f, 0.f};

    for (int e = 0; e < 8; e++) {
        const int slot = (e < 4) ? e : (4 + t * 4 + (e - 4));
        const unsigned short* bG0 = Wt + (size_t)slot * kDE * kD +
                                    (size_t)(n0 + srow) * kD + swzk;
        f32x4 acc[4][4];
#pragma unroll
        for (int m = 0; m < 4; m++)
#pragma unroll
            for (int n = 0; n < 4; n++) acc[m][n] = (f32x4){0.f, 0.f, 0.f, 0.f};

        for (int kt = 0; kt < 16; kt++) {
            const int k0 = kt * 64;
            __syncthreads();                       // prev compute done
#pragma unroll
            for (int i = 0; i < 4; i++) async16(aL + i * 512, aG0 + k0 + i * 8192);
#pragma unroll
            for (int i = 0; i < 4; i++) async16(bL + i * 512, bG0 + k0 + i * 8192);
            __syncthreads();                       // stage visible (vmcnt drained)
#pragma unroll
            for (int ks = 0; ks < 2; ks++) {
                const int cs = c0 ^ (ks << 5);
                bf16x8 af[4], bfr[4];
#pragma unroll
                for (int m = 0; m < 4; m++)
                    af[m] = *(const bf16x8*)&As[(rA + m * 16) * 64 + cs];
#pragma unroll
                for (int n = 0; n < 4; n++)
                    bfr[n] = *(const bf16x8*)&Bs[(rB + n * 16) * 64 + cs];
#pragma unroll
                for (int m = 0; m < 4; m++)
#pragma unroll
                    for (int n = 0; n < 4; n++)
                        acc[m][n] = __builtin_amdgcn_mfma_f32_16x16x32_bf16(
                            af[m], bfr[n], acc[m][n], 0, 0, 0);
            }
        }
        // epilogue for expert e: oacc += g * relu(acc + bias)
        const float* gE  = g  + (size_t)t * kB * 8 + e;
        const float* bcE = bc + (t * 8 + e) * kDE + n0 + wc * 64;
        float bv[4];
#pragma unroll
        for (int n = 0; n < 4; n++) bv[n] = bcE[n * 16 + (lane & 15)];
#pragma unroll
        for (int m = 0; m < 4; m++) {
            const int r0 = rowBase + wr * 64 + m * 16 + ((lane >> 4) << 2);
            float gv[4];
#pragma unroll
            for (int q = 0; q < 4; q++) gv[q] = gE[(size_t)(r0 + q) * 8];
#pragma unroll
            for (int n = 0; n < 4; n++)
#pragma unroll
                for (int q = 0; q < 4; q++)
                    oacc[m][n][q] += gv[q] * fmaxf(acc[m][n][q] + bv[n], 0.f);
        }
    }
    // store out[b][t][de]
#pragma unroll
    for (int m = 0; m < 4; m++) {
        const int r0 = rowBase + wr * 64 + m * 16 + ((lane >> 4) << 2);
#pragma unroll
        for (int n = 0; n < 4; n++) {
            const int col = n0 + wc * 64 + n * 16 + (lane & 15);
#pragma unroll
            for (int q = 0; q < 4; q++)
                out[((size_t)(r0 + q) * 2 + t) * kDE + col] = oacc[m][n][q];
        }
    }
}

extern "C" void kernel_launch(void* const* d_in, const int* in_sizes, int n_in,
                              void* d_out, int out_size, void* d_ws, size_t ws_size,
                              hipStream_t stream) {
    const float* x0  = (const float*)d_in[0];
    const float* x1  = (const float*)d_in[1];
    const float* Wsh = (const float*)d_in[2];
    const float* bsh = (const float*)d_in[3];
    const float* Wsp = (const float*)d_in[4];
    const float* bsp = (const float*)d_in[5];
    const float* Wg  = (const float*)d_in[6];
    const float* bg  = (const float*)d_in[7];
    float* out = (float*)d_out;

    // ws layout (bytes): xb 67108864 | Wt 12582912 | g 1048576 | bc 32768
    char* ws = (char*)d_ws;
    unsigned short* xb = (unsigned short*)ws;
    unsigned short* Wt = (unsigned short*)(ws + 67108864);
    float* g  = (float*)(ws + 67108864 + 12582912);
    float* bc = (float*)(ws + 67108864 + 12582912 + 1048576);

    prep_w<<<dim3(32, 16, 12), dim3(32, 8), 0, stream>>>(Wsh, Wsp, Wt);
    prep_b<<<dim3(32), dim3(256), 0, stream>>>(bsh, bsp, bc);
    conv_gate<<<dim3(8192), dim3(256), 0, stream>>>(x0, x1, Wg, bg, xb, g);
    moe_gemm<<<dim3(128, 4, 2), dim3(256), 0, stream>>>(xb, Wt, g, bc, out);
}

// Round 2
// 415.704 us; speedup vs baseline: 1.0310x; 1.0310x over previous
//
#include <hip/hip_runtime.h>
#include <stdint.h>

// Problem constants
#define kB  16384
#define kD  1024
#define kDE 512

typedef __bf16 bf16x8 __attribute__((ext_vector_type(8)));
typedef float  f32x4  __attribute__((ext_vector_type(4)));

__device__ __forceinline__ unsigned short f2bf(float f) {
    union { float f; unsigned u; } v; v.f = f;
    unsigned r = v.u + 0x7FFFu + ((v.u >> 16) & 1u);   // round-to-nearest-even
    return (unsigned short)(r >> 16);
}

__device__ __forceinline__ void async16(unsigned short* lds, const unsigned short* g) {
    __builtin_amdgcn_global_load_lds(
        (const __attribute__((address_space(1))) unsigned int*)g,
        (__attribute__((address_space(3))) unsigned int*)lds, 16, 0, 0);
}

// ---------------- prep: transpose + convert weights to bf16 ----------------
// Wt[slot][n=512][k=1024], slot: 0-3 shared, 4-7 t0-specific, 8-11 t1-specific
__global__ __launch_bounds__(256) void prep_w(const float* __restrict__ Wsh,
                                              const float* __restrict__ Wsp,
                                              unsigned short* __restrict__ Wt) {
    __shared__ float tile[32][33];
    const int slot = blockIdx.z;
    const int k0 = blockIdx.x * 32;
    const int n0 = blockIdx.y * 32;
    const float* src = (slot < 4) ? (Wsh + (size_t)slot * kD * kDE)
                                  : (Wsp + (size_t)(slot - 4) * kD * kDE);
    const int tx = threadIdx.x, ty = threadIdx.y;
#pragma unroll
    for (int i = 0; i < 4; i++)
        tile[ty + i * 8][tx] = src[(size_t)(k0 + ty + i * 8) * kDE + n0 + tx];
    __syncthreads();
    unsigned short* dst = Wt + (size_t)slot * kDE * kD;
#pragma unroll
    for (int i = 0; i < 4; i++)
        dst[(size_t)(n0 + ty + i * 8) * kD + k0 + tx] = f2bf(tile[tx][ty + i * 8]);
}

// bias concat: bc[t][e][n]  (2*8*512)
__global__ __launch_bounds__(256) void prep_b(const float* __restrict__ bsh,
                                              const float* __restrict__ bsp,
                                              float* __restrict__ bc) {
    int i = blockIdx.x * 256 + threadIdx.x;       // 0..8191
    int n = i & 511, e = (i >> 9) & 7, t = i >> 12;
    bc[i] = (e < 4) ? bsh[e * 512 + n] : bsp[(t * 4 + (e - 4)) * 512 + n];
}

// ------------- fused x fp32->bf16 conversion + gate softmax ---------------
// one wave per (t,b) row; xb[t][b][d] bf16; g[t][b][8] fp32
__global__ __launch_bounds__(256) void conv_gate(
    const float* __restrict__ x0, const float* __restrict__ x1,
    const float* __restrict__ Wg, const float* __restrict__ bg,
    unsigned short* __restrict__ xb, float* __restrict__ g) {
    const int wid = threadIdx.x >> 6, lane = threadIdx.x & 63;
    const int r = blockIdx.x * 4 + wid;           // 0..32767
    const int t = r >> 14, b = r & 16383;
    const float* xrow = (t ? x1 : x0) + (size_t)b * kD;
    unsigned short* xbrow = xb + (size_t)(t * kB + b) * kD;
    const float* Wgt = Wg + t * kD * 8;
    float p[8] = {0.f,0.f,0.f,0.f,0.f,0.f,0.f,0.f};
#pragma unroll
    for (int it = 0; it < 4; it++) {
        const int d0 = it * 256 + lane * 4;
        const float4 v = *(const float4*)(xrow + d0);
        ushort4 h;
        h.x = f2bf(v.x); h.y = f2bf(v.y); h.z = f2bf(v.z); h.w = f2bf(v.w);
        *(ushort4*)(xbrow + d0) = h;
        const float xv[4] = {v.x, v.y, v.z, v.w};
#pragma unroll
        for (int j = 0; j < 4; j++) {
            const float* wrow = Wgt + (size_t)(d0 + j) * 8;
#pragma unroll
            for (int e = 0; e < 8; e++) p[e] += xv[j] * wrow[e];
        }
    }
#pragma unroll
    for (int e = 0; e < 8; e++) {
        float v = p[e];
#pragma unroll
        for (int s = 1; s < 64; s <<= 1) v += __shfl_xor(v, s, 64);
        p[e] = v;
    }
    float lg[8];
#pragma unroll
    for (int e = 0; e < 8; e++) lg[e] = p[e] + bg[t * 8 + e];
    float mx = lg[0];
#pragma unroll
    for (int e = 1; e < 8; e++) mx = fmaxf(mx, lg[e]);
    float s = 0.f;
#pragma unroll
    for (int e = 0; e < 8; e++) { lg[e] = __expf(lg[e] - mx); s += lg[e]; }
    const float inv = 1.f / s;
    if (lane == 0) {
        float* gp = g + (size_t)(t * kB + b) * 8;
        float4 g0 = {lg[0]*inv, lg[1]*inv, lg[2]*inv, lg[3]*inv};
        float4 g1 = {lg[4]*inv, lg[5]*inv, lg[6]*inv, lg[7]*inv};
        *(float4*)gp = g0;
        *(float4*)(gp + 4) = g1;
    }
}

// --------------------------- fused MoE GEMM -------------------------------
// Experts INNER: block tile M=128 rows x (N=64 cols shared by all 8 experts).
// 8 waves (2 M-halves x 4 N-quarters); per-wave 64x16 per expert.
// BK=64, double-buffered 160KB LDS, counted vmcnt(10) (T3-min pipeline),
// XOR-swizzled LDS via pre-swizzled global source (rule #21).
__global__ __launch_bounds__(512, 2) void moe_gemm(
    const unsigned short* __restrict__ xb, const unsigned short* __restrict__ Wt,
    const float* __restrict__ g, const float* __restrict__ bc,
    float* __restrict__ out) {
    __shared__ __align__(16) unsigned short As[2][128 * 64];      // 32 KB
    __shared__ __align__(16) unsigned short Bs[2][8 * 64 * 64];   // 128 KB

    // XCD-bijective swizzle: nwg=2048 (=0 mod 8). work = ((t*128+rt)*8+ct)
    const int bid = blockIdx.x;
    const int swz = (bid & 7) * 256 + (bid >> 3);
    const int ct = swz & 7;
    const int rt = (swz >> 3) & 127;
    const int t  = swz >> 10;
    const int n0 = ct * 64;

    const int tid = threadIdx.x, wid = tid >> 6, lane = tid & 63;
    const int wr = wid >> 2, wc = wid & 3;

    // ---- staging addresses (pre-swizzled source, linear LDS dest) ----
    const int swzChunk = ((lane & 7) ^ ((lane >> 3) & 7)) * 8;    // element offset
    // A: wave wid stages rows [wid*16, +16)
    const unsigned short* aSrc = xb + (size_t)t * kB * kD +
        (size_t)(rt * 128 + wid * 16 + (lane >> 3)) * kD + swzChunk;
    // B: wave wid stages expert wid's 64x64 tile
    const int slot = (wid < 4) ? wid : (4 + t * 4 + (wid - 4));
    const unsigned short* bSrc = Wt + (size_t)slot * kDE * kD +
        (size_t)(n0 + (lane >> 3)) * kD + swzChunk;

    // ---- fragment read offsets ----
    const int rAbase = (wr * 64 + (lane & 15)) * 64;              // + m*1024 + p*8
    const int bOff   = (wc * 16 + (lane & 15)) * 64;              // + e*4096 + p*8
    const int lx     = lane & 7;
    const int kg     = lane >> 4;                                  // 0..3

    f32x4 acc[8][4];
#pragma unroll
    for (int e = 0; e < 8; e++)
#pragma unroll
        for (int m = 0; m < 4; m++) acc[e][m] = (f32x4){0.f, 0.f, 0.f, 0.f};

#define STAGE(buf, kt)                                                        \
    {                                                                         \
        const int k0_ = (kt) * 64;                                            \
        _Pragma("unroll")                                                     \
        for (int i = 0; i < 2; i++)                                           \
            async16(&As[buf][wid * 1024 + i * 512], aSrc + k0_ + i * 8 * kD); \
        _Pragma("unroll")                                                     \
        for (int j = 0; j < 8; j++)                                           \
            async16(&Bs[buf][wid * 4096 + j * 512], bSrc + k0_ + j * 8 * kD); \
    }

#define COMPUTE(buf)                                                          \
    {                                                                         \
        _Pragma("unroll")                                                     \
        for (int ks = 0; ks < 2; ks++) {                                      \
            const int p8 = ((ks * 4 + kg) ^ lx) * 8;                          \
            bf16x8 af[4];                                                     \
            _Pragma("unroll")                                                 \
            for (int m = 0; m < 4; m++)                                       \
                af[m] = *(const bf16x8*)&As[buf][rAbase + m * 1024 + p8];     \
            _Pragma("unroll")                                                 \
            for (int e = 0; e < 8; e++) {                                     \
                bf16x8 bf = *(const bf16x8*)&Bs[buf][e * 4096 + bOff + p8];   \
                _Pragma("unroll")                                             \
                for (int m = 0; m < 4; m++)                                   \
                    acc[e][m] = __builtin_amdgcn_mfma_f32_16x16x32_bf16(      \
                        af[m], bf, acc[e][m], 0, 0, 0);                       \
            }                                                                 \
        }                                                                     \
    }

    STAGE(0, 0);                                   // 10 loads in flight
    for (int kt = 0; kt < 15; ++kt) {
        STAGE((kt + 1) & 1, kt + 1);               // +10 -> 20 in flight
        asm volatile("s_waitcnt vmcnt(10)" ::: "memory");   // tile kt done
        __builtin_amdgcn_s_barrier();
        COMPUTE(kt & 1);
        __builtin_amdgcn_s_barrier();              // all reads done before overwrite
    }
    asm volatile("s_waitcnt vmcnt(0)" ::: "memory");
    __builtin_amdgcn_s_barrier();
    COMPUTE(1);

    // ---- epilogue: oacc[m] = sum_e g_e * relu(acc[e][m] + b_e) ----
    const int col = n0 + wc * 16 + (lane & 15);
    float bv[8];
#pragma unroll
    for (int e = 0; e < 8; e++) bv[e] = bc[(t * 8 + e) * kDE + col];

#pragma unroll
    for (int m = 0; m < 4; m++) {
        const int r0 = rt * 128 + wr * 64 + m * 16 + kg * 4;
        f32x4 oq = (f32x4){0.f, 0.f, 0.f, 0.f};
#pragma unroll
        for (int q = 0; q < 4; q++) {
            const float* gp = g + ((size_t)t * kB + r0 + q) * 8;
            const float4 ga = *(const float4*)gp;
            const float4 gb = *(const float4*)(gp + 4);
            const float gv[8] = {ga.x, ga.y, ga.z, ga.w, gb.x, gb.y, gb.z, gb.w};
            float s = 0.f;
#pragma unroll
            for (int e = 0; e < 8; e++)
                s += gv[e] * fmaxf(acc[e][m][q] + bv[e], 0.f);
            oq[q] = s;
        }
#pragma unroll
        for (int q = 0; q < 4; q++)
            out[((size_t)(r0 + q) * 2 + t) * kDE + col] = oq[q];
    }
#undef STAGE
#undef COMPUTE
}

extern "C" void kernel_launch(void* const* d_in, const int* in_sizes, int n_in,
                              void* d_out, int out_size, void* d_ws, size_t ws_size,
                              hipStream_t stream) {
    const float* x0  = (const float*)d_in[0];
    const float* x1  = (const float*)d_in[1];
    const float* Wsh = (const float*)d_in[2];
    const float* bsh = (const float*)d_in[3];
    const float* Wsp = (const float*)d_in[4];
    const float* bsp = (const float*)d_in[5];
    const float* Wg  = (const float*)d_in[6];
    const float* bg  = (const float*)d_in[7];
    float* out = (float*)d_out;

    // ws layout (bytes): xb 67108864 | Wt 12582912 | g 1048576 | bc 32768
    char* ws = (char*)d_ws;
    unsigned short* xb = (unsigned short*)ws;
    unsigned short* Wt = (unsigned short*)(ws + 67108864);
    float* g  = (float*)(ws + 67108864 + 12582912);
    float* bc = (float*)(ws + 67108864 + 12582912 + 1048576);

    prep_w<<<dim3(32, 16, 12), dim3(32, 8), 0, stream>>>(Wsh, Wsp, Wt);
    prep_b<<<dim3(32), dim3(256), 0, stream>>>(bsh, bsp, bc);
    conv_gate<<<dim3(8192), dim3(256), 0, stream>>>(x0, x1, Wg, bg, xb, g);
    moe_gemm<<<dim3(2048), dim3(512), 0, stream>>>(xb, Wt, g, bc, out);
}